// Round 2
// baseline (1155.421 us; speedup 1.0000x reference)
//
#include <hip/hip_runtime.h>
#include <hip/hip_bf16.h>

#define BB 512
#define TT 256
#define VV 128
#define EE 64
#define HH 64
#define GG 256   // 4H
#define DD 128   // 2H
#define NN1 512  // 2 dirs * 4H

__device__ __forceinline__ float sigf(float x){ return 1.0f/(1.0f + __expf(-x)); }
__device__ __forceinline__ float tanhfast(float x){ return 1.0f - 2.0f/(__expf(2.0f*x)+1.0f); }
__device__ __forceinline__ unsigned short f2bf(float f){
  unsigned int u = __float_as_uint(f);
  u += 0x7fffu + ((u >> 16) & 1u);
  return (unsigned short)(u >> 16);
}
__device__ __forceinline__ float bf2f(unsigned short u){
  return __uint_as_float(((unsigned int)u) << 16);
}

// ---------------- prep: embproj tables, transposed weights, exp(trans) ----------------
__global__ void k_prep(const float* __restrict__ emb,
    const float* __restrict__ wih0f, const float* __restrict__ bih0f, const float* __restrict__ bhh0f,
    const float* __restrict__ wih0b, const float* __restrict__ bih0b, const float* __restrict__ bhh0b,
    const float* __restrict__ wih1f, const float* __restrict__ bih1f, const float* __restrict__ bhh1f,
    const float* __restrict__ wih1b, const float* __restrict__ bih1b, const float* __restrict__ bhh1b,
    const float* __restrict__ lin_w, const float* __restrict__ trans, const float* __restrict__ endv,
    float* __restrict__ P0f, float* __restrict__ P0b, float* __restrict__ wT1,
    float* __restrict__ linT, float* __restrict__ bias1,
    float* __restrict__ etrans, float* __restrict__ eend)
{
  int bid = blockIdx.x, tid = threadIdx.x;
  if (bid < 256){
    // embproj: P0[d][v][g] = emb[v,:]·wih[g,:] + b_ih[g] + b_hh[g]
    int d = bid >> 7, v = bid & 127;
    const float* wih = d ? wih0b : wih0f;
    const float* bi  = d ? bih0b : bih0f;
    const float* bh  = d ? bhh0b : bhh0f;
    float* P0 = d ? P0b : P0f;
    __shared__ __align__(16) float er[64];
    if (tid < 64) er[tid] = emb[v*64 + tid];
    __syncthreads();
    float acc = bi[tid] + bh[tid];
    const float4* w4 = (const float4*)(wih + tid*64);
    const float4* e4 = (const float4*)er;
    #pragma unroll
    for (int k=0;k<16;k++){
      float4 w = w4[k]; float4 e = e4[k];
      acc += w.x*e.x + w.y*e.y + w.z*e.z + w.w*e.w;
    }
    P0[v*GG + tid] = acc;
  } else if (bid < 512){
    // wT1[k][d*256+g] = w_ih_l1{d}[g][k]   (128 x 512)
    int idx = (bid-256)*256 + tid;
    int k = idx >> 9, col = idx & 511;
    int d = col >> 8, gg = col & 255;
    const float* w = d ? wih1b : wih1f;
    wT1[idx] = w[gg*128 + k];
  } else if (bid < 576){
    // linT[k][v] = lin_w[v][k]   (128 x 128)
    int idx = (bid-512)*256 + tid;
    int k = idx >> 7, v = idx & 127;
    linT[idx] = lin_w[v*128 + k];
  } else if (bid < 640){
    int idx = (bid-576)*256 + tid;
    etrans[idx] = expf(trans[idx]);
  } else {
    for (int i = tid; i < 512; i += 256){
      int d = i >> 8, gg = i & 255;
      bias1[i] = d ? (bih1b[gg]+bhh1b[gg]) : (bih1f[gg]+bhh1f[gg]);
    }
    if (tid < 128) eend[tid] = expf(endv[tid]);
  }
}

// ---------------- LSTM recurrence: 1 block = 2 batch rows, thread = gate ----------------
template<int LAYER>
__global__ __launch_bounds__(256, 2)
void k_lstm(const int* __restrict__ x, const float* __restrict__ P0f,
            const float* __restrict__ P0b, const unsigned short* __restrict__ pre1,
            const float* __restrict__ whhf, const float* __restrict__ whhb,
            unsigned short* __restrict__ hout)
{
  const int bid = blockIdx.x;        // 0..511
  const int dir = bid >> 8;          // 0 fwd, 1 bwd
  const int b0 = (bid & 255) * 2;
  const int b1 = b0 + 1;
  const int g = threadIdx.x;         // gate 0..255
  const float* whh = dir ? whhb : whhf;
  float w[64];
  {
    const float4* wp = (const float4*)(whh + g*64);
    #pragma unroll
    for (int k=0;k<16;k++){ float4 v = wp[k]; w[4*k]=v.x; w[4*k+1]=v.y; w[4*k+2]=v.z; w[4*k+3]=v.w; }
  }
  __shared__ float4 hsh[2][16];      // h state (2 rows x 64)
  __shared__ float  csh[2][64];
  __shared__ float  gbuf[2][256];
  if (g < 128){
    int b = g>>6, j = g&63;
    ((float*)hsh)[b*64+j] = 0.f;
    csh[b][j] = 0.f;
  }
  __syncthreads();

  const float* P0 = dir ? P0b : P0f;
  const int tt0 = dir ? (TT-1) : 0;
  float pc0, pc1;
  if (LAYER == 0){
    int i0 = x[b0*TT + tt0], i1 = x[b1*TT + tt0];
    pc0 = P0[i0*GG + g]; pc1 = P0[i1*GG + g];
  } else {
    pc0 = bf2f(pre1[(size_t)(b0*TT + tt0)*NN1 + dir*GG + g]);
    pc1 = bf2f(pre1[(size_t)(b1*TT + tt0)*NN1 + dir*GG + g]);
  }
  float rn0 = 0.f, rn1 = 0.f;
  int idxn0 = 0, idxn1 = 0;

  for (int t=0;t<TT;t++){
    const int tt  = dir ? (TT-1-t) : t;
    const int ttn = dir ? (tt-1) : (tt+1);
    const bool more = (t < TT-1);
    if (LAYER == 0){
      if (more){ idxn0 = x[b0*TT + ttn]; idxn1 = x[b1*TT + ttn]; }
    } else {
      if (more){
        rn0 = bf2f(pre1[(size_t)(b0*TT + ttn)*NN1 + dir*GG + g]);
        rn1 = bf2f(pre1[(size_t)(b1*TT + ttn)*NN1 + dir*GG + g]);
      }
    }
    float a0 = 0.f, a1 = 0.f;
    #pragma unroll
    for (int k=0;k<16;k++){
      float4 h0 = hsh[0][k], h1 = hsh[1][k];
      a0 = fmaf(h0.x, w[4*k+0], a0);  a1 = fmaf(h1.x, w[4*k+0], a1);
      a0 = fmaf(h0.y, w[4*k+1], a0);  a1 = fmaf(h1.y, w[4*k+1], a1);
      a0 = fmaf(h0.z, w[4*k+2], a0);  a1 = fmaf(h1.z, w[4*k+2], a1);
      a0 = fmaf(h0.w, w[4*k+3], a0);  a1 = fmaf(h1.w, w[4*k+3], a1);
    }
    if (LAYER == 0){
      if (more){ rn0 = P0[idxn0*GG + g]; rn1 = P0[idxn1*GG + g]; }
    }
    gbuf[0][g] = a0 + pc0;
    gbuf[1][g] = a1 + pc1;
    __syncthreads();
    if (g < 128){
      int b = g>>6, j = g&63;
      float gi = gbuf[b][j], gf = gbuf[b][64+j], gc = gbuf[b][128+j], go = gbuf[b][192+j];
      float c = csh[b][j];
      float cn = sigf(gf)*c + sigf(gi)*tanhfast(gc);
      float hn = sigf(go)*tanhfast(cn);
      csh[b][j] = cn;
      ((float*)hsh)[b*64+j] = hn;
      hout[(size_t)((b0 + b)*TT + tt)*DD + dir*HH + j] = f2bf(hn);
    }
    __syncthreads();
    pc0 = rn0; pc1 = rn1;
  }
}

// ---- SGEMM: C[M x N] = A[M x 128](bf16) @ B[128 x N](f32) + bias, M=131072 ----
// LDS: As 64x132 bf16 (16.5 KiB) + Bs 128x64 f32 (32 KiB) = 49.7 KiB < 64 KiB.
__global__ __launch_bounds__(256, 2)
void k_gemm(const unsigned short* __restrict__ A, const float* __restrict__ Bm,
            const float* __restrict__ bias, void* __restrict__ C,
            const int N, const int obf16)
{
  const int nb = blockIdx.x, mb = blockIdx.y;
  const int tid = threadIdx.x;
  __shared__ __align__(16) unsigned short As[64*132];
  __shared__ __align__(16) float Bs[128*64];
  const size_t m0 = (size_t)mb * 64;
  const int n0 = nb * 64;
  {
    const ushort4* Ag = (const ushort4*)(A + m0*128);
    #pragma unroll
    for (int i=0;i<8;i++){
      int idx = tid + i*256;           // 2048 ushort4s = 64x128 bf16
      int r = idx >> 5, c = idx & 31;
      ushort4 v = Ag[r*32 + c];
      *((ushort4*)(As + r*132 + c*4)) = v;
    }
  }
  {
    #pragma unroll
    for (int i=0;i<8;i++){
      int idx = tid + i*256;           // 2048 float4s = 128x64 floats
      int r = idx >> 4, c = idx & 15;
      float4 v = *((const float4*)(Bm + (size_t)r*N + n0 + c*4));
      *((float4*)(Bs + r*64 + c*4)) = v;
    }
  }
  __syncthreads();
  const int tx = tid & 15, ty = tid >> 4;
  float acc[4][4];
  #pragma unroll
  for (int i=0;i<4;i++)
    #pragma unroll
    for (int j=0;j<4;j++) acc[i][j] = 0.f;

  #pragma unroll 4
  for (int k4=0;k4<32;k4++){
    float a[4][4]; float4 b[4];
    #pragma unroll
    for (int i=0;i<4;i++){
      ushort4 ua = *((const ushort4*)(As + (ty*4+i)*132 + k4*4));
      a[i][0]=bf2f(ua.x); a[i][1]=bf2f(ua.y); a[i][2]=bf2f(ua.z); a[i][3]=bf2f(ua.w);
    }
    #pragma unroll
    for (int u=0;u<4;u++) b[u] = *((const float4*)(Bs + (k4*4+u)*64 + tx*4));
    #pragma unroll
    for (int i=0;i<4;i++){
      #pragma unroll
      for (int u=0;u<4;u++){
        float av = a[i][u];
        acc[i][0]=fmaf(av,b[u].x,acc[i][0]); acc[i][1]=fmaf(av,b[u].y,acc[i][1]);
        acc[i][2]=fmaf(av,b[u].z,acc[i][2]); acc[i][3]=fmaf(av,b[u].w,acc[i][3]);
      }
    }
  }
  float4 bv = *((const float4*)(bias + n0 + tx*4));
  #pragma unroll
  for (int i=0;i<4;i++){
    size_t m = m0 + ty*4 + i;
    float o0 = acc[i][0]+bv.x, o1 = acc[i][1]+bv.y, o2 = acc[i][2]+bv.z, o3 = acc[i][3]+bv.w;
    if (obf16){
      ushort4 s; s.x=f2bf(o0); s.y=f2bf(o1); s.z=f2bf(o2); s.w=f2bf(o3);
      *((ushort4*)((unsigned short*)C + m*N + n0 + tx*4)) = s;
    } else {
      float4 o; o.x=o0; o.y=o1; o.z=o2; o.w=o3;
      *((float4*)((float*)C + m*N + n0 + tx*4)) = o;
    }
  }
}

// ---------------- gold-path score: 1 block (64 thr) per batch row ----------------
__global__ void k_score(const int* __restrict__ x, const int* __restrict__ tags,
                        const float* __restrict__ em, const float* __restrict__ startv,
                        const float* __restrict__ endv, const float* __restrict__ trans,
                        float* __restrict__ score)
{
  int b = blockIdx.x, lane = threadIdx.x;
  float s = 0.f; int cnt = 0;
  for (int t = lane; t < TT; t += 64){
    int xv = x[b*TT + t];
    int m = (xv != 0);
    cnt += m;
    if (t >= 1 && m){
      int tp = tags[b*TT + t - 1], tc = tags[b*TT + t];
      s += trans[tp*VV + tc] + em[(size_t)(b*TT + t)*VV + tc];
    }
  }
  #pragma unroll
  for (int o=32;o>0;o>>=1){ s += __shfl_down(s,o,64); cnt += __shfl_down(cnt,o,64); }
  if (lane==0){
    int t0 = tags[b*TT];
    s += startv[t0] + em[(size_t)(b*TT)*VV + t0];
    int lt = tags[b*TT + cnt - 1];
    s += endv[lt];
    score[b] = s;
  }
}

// ---------------- CRF partition scan in linear domain: 1 block per batch row ----------------
__global__ __launch_bounds__(256,2)
void k_crf(const int* __restrict__ x, const float* __restrict__ em,
           const float* __restrict__ etrans, const float* __restrict__ startv,
           const float* __restrict__ eend, float* __restrict__ part)
{
  const int b = blockIdx.x;
  const int j = threadIdx.x & 127;
  const int ih = threadIdx.x >> 7;     // i-range half
  const int wid = threadIdx.x >> 6;
  const int lane = threadIdx.x & 63;
  float et[64];
  #pragma unroll
  for (int u=0;u<64;u++) et[u] = etrans[(ih*64+u)*VV + j];
  __shared__ __align__(16) float abuf[128];
  __shared__ float spbuf[128];
  __shared__ float red[4];
  float L = 0.f, myA = 0.f;
  {
    float e = 0.f;
    if (ih==0){
      e = __expf(startv[j] + em[(size_t)(b*TT)*VV + j]);
      float wsum = e;
      #pragma unroll
      for (int o=32;o>0;o>>=1) wsum += __shfl_down(wsum,o,64);
      if (lane==0) red[wid] = wsum;
    }
    __syncthreads();
    float Z = red[0]+red[1];
    L = logf(Z);
    if (ih==0){ myA = e/Z; abuf[j] = myA; }
    __syncthreads();
  }
  for (int t=1;t<TT;t++){
    if (x[b*TT + t] == 0) break;       // mask is a contiguous prefix
    float emv = 0.f;
    if (ih==0) emv = em[(size_t)(b*TT + t)*VV + j];
    float s = 0.f;
    const float4* av = (const float4*)(abuf + ih*64);
    #pragma unroll
    for (int i4=0;i4<16;i4++){
      float4 a = av[i4];
      s = fmaf(a.x, et[4*i4+0], s);
      s = fmaf(a.y, et[4*i4+1], s);
      s = fmaf(a.z, et[4*i4+2], s);
      s = fmaf(a.w, et[4*i4+3], s);
    }
    if (ih==1) spbuf[j] = s;
    __syncthreads();
    float raw = 0.f;
    if (ih==0){
      raw = (s + spbuf[j]) * __expf(emv);
      float wsum = raw;
      #pragma unroll
      for (int o=32;o>0;o>>=1) wsum += __shfl_down(wsum,o,64);
      if (lane==0) red[wid] = wsum;
    }
    __syncthreads();
    float Zt = red[0]+red[1];
    L += logf(Zt);
    if (ih==0){ myA = raw/Zt; abuf[j] = myA; }
    __syncthreads();
  }
  {
    float v = 0.f;
    if (ih==0){
      v = myA * eend[j];
      #pragma unroll
      for (int o=32;o>0;o>>=1) v += __shfl_down(v,o,64);
      if (lane==0) red[wid] = v;
    }
    __syncthreads();
    if (threadIdx.x==0) part[b] = L + logf(red[0]+red[1]);
  }
}

__global__ void k_final(const float* __restrict__ part, const float* __restrict__ score,
                        float* __restrict__ out)
{
  __shared__ float red[8];
  int tid = threadIdx.x;
  float v = part[tid] - score[tid];
  #pragma unroll
  for (int o=32;o>0;o>>=1) v += __shfl_down(v,o,64);
  if ((tid&63)==0) red[tid>>6] = v;
  __syncthreads();
  if (tid==0){
    float s = 0.f;
    #pragma unroll
    for (int i=0;i<8;i++) s += red[i];
    out[0] = s / (float)BB;
  }
}

extern "C" void kernel_launch(void* const* d_in, const int* in_sizes, int n_in,
                              void* d_out, int out_size, void* d_ws, size_t ws_size,
                              hipStream_t stream)
{
  const int*   x        = (const int*)d_in[0];
  const int*   tags     = (const int*)d_in[1];
  const float* emb      = (const float*)d_in[2];
  const float* w_ih_l0  = (const float*)d_in[3];
  const float* w_hh_l0  = (const float*)d_in[4];
  const float* b_ih_l0  = (const float*)d_in[5];
  const float* b_hh_l0  = (const float*)d_in[6];
  const float* w_ih_l0r = (const float*)d_in[7];
  const float* w_hh_l0r = (const float*)d_in[8];
  const float* b_ih_l0r = (const float*)d_in[9];
  const float* b_hh_l0r = (const float*)d_in[10];
  const float* w_ih_l1  = (const float*)d_in[11];
  const float* w_hh_l1  = (const float*)d_in[12];
  const float* b_ih_l1  = (const float*)d_in[13];
  const float* b_hh_l1  = (const float*)d_in[14];
  const float* w_ih_l1r = (const float*)d_in[15];
  const float* w_hh_l1r = (const float*)d_in[16];
  const float* b_ih_l1r = (const float*)d_in[17];
  const float* b_hh_l1r = (const float*)d_in[18];
  const float* lin_w    = (const float*)d_in[19];
  const float* lin_b    = (const float*)d_in[20];
  const float* crf_start= (const float*)d_in[21];
  const float* crf_end  = (const float*)d_in[22];
  const float* crf_trans= (const float*)d_in[23];

  char* ws = (char*)d_ws;
  float* P0f    = (float*)(ws + 0);         // 128*256*4 = 131072
  float* P0b    = (float*)(ws + 131072);
  float* wT1    = (float*)(ws + 262144);    // 128*512*4 = 262144
  float* linT   = (float*)(ws + 524288);    // 65536
  float* bias1  = (float*)(ws + 589824);    // 2048
  float* etrans = (float*)(ws + 591872);    // 65536
  float* eend   = (float*)(ws + 657408);    // 512
  float* scoreA = (float*)(ws + 657920);    // 2048
  float* partA  = (float*)(ws + 659968);    // 2048
  const size_t MB1 = 1ull<<20;
  // hbuf: 32 MiB bf16 (B*T*128); reused for h0out (layer0->gemm1) then h1out (lstm1->gemm2)
  unsigned short* hbuf = (unsigned short*)(ws + MB1);
  // pre1: 128 MiB bf16 (B*T*512) at 33 MiB; em (f32, 64 MiB) aliases it (pre1 dead by then)
  unsigned short* pre1 = (unsigned short*)(ws + MB1 + 33554432ull);
  float* em            = (float*)(ws + MB1 + 33554432ull);
  // total footprint: 1 MiB + 32 MiB + 128 MiB = 161 MiB

  k_prep<<<dim3(641), dim3(256), 0, stream>>>(
      emb, w_ih_l0,b_ih_l0,b_hh_l0, w_ih_l0r,b_ih_l0r,b_hh_l0r,
      w_ih_l1,b_ih_l1,b_hh_l1, w_ih_l1r,b_ih_l1r,b_hh_l1r,
      lin_w, crf_trans, crf_end,
      P0f,P0b,wT1,linT,bias1,etrans,eend);

  k_lstm<0><<<dim3(512), dim3(256), 0, stream>>>(
      x, P0f, P0b, pre1, w_hh_l0, w_hh_l0r, hbuf);

  k_gemm<<<dim3(8,2048), dim3(256), 0, stream>>>(
      hbuf, wT1, bias1, (void*)pre1, 512, 1);

  k_lstm<1><<<dim3(512), dim3(256), 0, stream>>>(
      x, P0f, P0b, pre1, w_hh_l1, w_hh_l1r, hbuf);

  k_gemm<<<dim3(2,2048), dim3(256), 0, stream>>>(
      hbuf, linT, lin_b, (void*)em, 128, 0);

  k_score<<<dim3(512), dim3(64), 0, stream>>>(
      x, tags, em, crf_start, crf_end, crf_trans, scoreA);

  k_crf<<<dim3(512), dim3(256), 0, stream>>>(
      x, em, etrans, crf_start, eend, partA);

  k_final<<<dim3(1), dim3(512), 0, stream>>>(partA, scoreA, (float*)d_out);
}

// Round 3
// 981.321 us; speedup vs baseline: 1.1774x; 1.1774x over previous
//
#include <hip/hip_runtime.h>
#include <hip/hip_bf16.h>

#define BB 512
#define TT 256
#define VV 128
#define EE 64
#define HH 64
#define GG 256   // 4H
#define DD 128   // 2H
#define NN1 512  // 2 dirs * 4H

typedef unsigned short ushort8_t __attribute__((ext_vector_type(8)));
typedef short s8v __attribute__((ext_vector_type(8)));
typedef float f4v __attribute__((ext_vector_type(4)));

__device__ __forceinline__ float sigf(float x){ return 1.0f/(1.0f + __expf(-x)); }
__device__ __forceinline__ float tanhfast(float x){ return 1.0f - 2.0f/(__expf(2.0f*x)+1.0f); }
__device__ __forceinline__ unsigned short f2bf(float f){
  unsigned int u = __float_as_uint(f);
  u += 0x7fffu + ((u >> 16) & 1u);
  return (unsigned short)(u >> 16);
}
__device__ __forceinline__ float bf2f(unsigned short u){
  return __uint_as_float(((unsigned int)u) << 16);
}

// ---------------- prep: embproj tables, bf16 weights, exp(trans) ----------------
__global__ void k_prep(const float* __restrict__ emb,
    const float* __restrict__ wih0f, const float* __restrict__ bih0f, const float* __restrict__ bhh0f,
    const float* __restrict__ wih0b, const float* __restrict__ bih0b, const float* __restrict__ bhh0b,
    const float* __restrict__ wih1f, const float* __restrict__ bih1f, const float* __restrict__ bhh1f,
    const float* __restrict__ wih1b, const float* __restrict__ bih1b, const float* __restrict__ bhh1b,
    const float* __restrict__ lin_w, const float* __restrict__ trans, const float* __restrict__ endv,
    float* __restrict__ P0f, float* __restrict__ P0b,
    unsigned short* __restrict__ wB1, unsigned short* __restrict__ linB,
    float* __restrict__ bias1, float* __restrict__ etrans, float* __restrict__ eend)
{
  int bid = blockIdx.x, tid = threadIdx.x;
  if (bid < 256){
    // embproj: P0[d][v][g] = emb[v,:]·wih[g,:] + b_ih[g] + b_hh[g]
    int d = bid >> 7, v = bid & 127;
    const float* wih = d ? wih0b : wih0f;
    const float* bi  = d ? bih0b : bih0f;
    const float* bh  = d ? bhh0b : bhh0f;
    float* P0 = d ? P0b : P0f;
    __shared__ __align__(16) float er[64];
    if (tid < 64) er[tid] = emb[v*64 + tid];
    __syncthreads();
    float acc = bi[tid] + bh[tid];
    const float4* w4 = (const float4*)(wih + tid*64);
    const float4* e4 = (const float4*)er;
    #pragma unroll
    for (int k=0;k<16;k++){
      float4 w = w4[k]; float4 e = e4[k];
      acc += w.x*e.x + w.y*e.y + w.z*e.z + w.w*e.w;
    }
    P0[v*GG + tid] = acc;
  } else if (bid < 320){
    // wB1[n][k] bf16, n = dir*256+g over [512], k over [128]
    int e = ((bid-256)*256 + tid)*4;
    int n = e >> 7, k = e & 127;
    const float* w = (n < 256) ? (wih1f + n*128 + k) : (wih1b + (n-256)*128 + k);
    ushort4 o; o.x=f2bf(w[0]); o.y=f2bf(w[1]); o.z=f2bf(w[2]); o.w=f2bf(w[3]);
    *(ushort4*)(wB1 + e) = o;
  } else if (bid < 336){
    // linB[v][k] bf16 (128 x 128)
    int e = ((bid-320)*256 + tid)*4;
    const float* w = lin_w + e;
    ushort4 o; o.x=f2bf(w[0]); o.y=f2bf(w[1]); o.z=f2bf(w[2]); o.w=f2bf(w[3]);
    *(ushort4*)(linB + e) = o;
  } else if (bid < 400){
    int idx = (bid-336)*256 + tid;   // 0..16383
    etrans[idx] = expf(trans[idx]);
  } else {
    for (int i = tid; i < 512; i += 256){
      int d = i >> 8, gg = i & 255;
      bias1[i] = d ? (bih1b[gg]+bhh1b[gg]) : (bih1f[gg]+bhh1f[gg]);
    }
    if (tid < 128) eend[tid] = expf(endv[tid]);
  }
}

// ---------------- LSTM recurrence: 1 block = 2 batch rows, thread = gate ----------------
template<int LAYER>
__global__ __launch_bounds__(256, 2)
void k_lstm(const int* __restrict__ x, const float* __restrict__ P0f,
            const float* __restrict__ P0b, const unsigned short* __restrict__ pre1,
            const float* __restrict__ whhf, const float* __restrict__ whhb,
            unsigned short* __restrict__ hout)
{
  const int bid = blockIdx.x;        // 0..511
  const int dir = bid >> 8;          // 0 fwd, 1 bwd
  const int b0 = (bid & 255) * 2;
  const int b1 = b0 + 1;
  const int g = threadIdx.x;         // gate 0..255
  const float* whh = dir ? whhb : whhf;
  float w[64];
  {
    const float4* wp = (const float4*)(whh + g*64);
    #pragma unroll
    for (int k=0;k<16;k++){ float4 v = wp[k]; w[4*k]=v.x; w[4*k+1]=v.y; w[4*k+2]=v.z; w[4*k+3]=v.w; }
  }
  // Pin w[] into VGPRs: without this LLVM rematerializes the whh loads into the
  // t-loop (VGPR_Count=48 observed) and re-fetches 64 KB/CU of weights per step.
  #pragma unroll
  for (int k=0;k<64;k++) asm volatile("" : "+v"(w[k]));

  __shared__ float4 hsh[2][16];      // h state (2 rows x 64)
  __shared__ float  csh[2][64];
  __shared__ float  gbuf[2][256];
  if (g < 128){
    int b = g>>6, j = g&63;
    ((float*)hsh)[b*64+j] = 0.f;
    csh[b][j] = 0.f;
  }
  __syncthreads();

  const float* P0 = dir ? P0b : P0f;
  const int tt0 = dir ? (TT-1) : 0;
  float pc0, pc1;
  if (LAYER == 0){
    int i0 = x[b0*TT + tt0], i1 = x[b1*TT + tt0];
    pc0 = P0[i0*GG + g]; pc1 = P0[i1*GG + g];
  } else {
    pc0 = bf2f(pre1[(size_t)(b0*TT + tt0)*NN1 + dir*GG + g]);
    pc1 = bf2f(pre1[(size_t)(b1*TT + tt0)*NN1 + dir*GG + g]);
  }
  float rn0 = 0.f, rn1 = 0.f;
  int idxn0 = 0, idxn1 = 0;

  for (int t=0;t<TT;t++){
    const int tt  = dir ? (TT-1-t) : t;
    const int ttn = dir ? (tt-1) : (tt+1);
    const bool more = (t < TT-1);
    if (LAYER == 0){
      if (more){ idxn0 = x[b0*TT + ttn]; idxn1 = x[b1*TT + ttn]; }
    } else {
      if (more){
        rn0 = bf2f(pre1[(size_t)(b0*TT + ttn)*NN1 + dir*GG + g]);
        rn1 = bf2f(pre1[(size_t)(b1*TT + ttn)*NN1 + dir*GG + g]);
      }
    }
    float a0 = 0.f, a1 = 0.f;
    #pragma unroll
    for (int k=0;k<16;k++){
      float4 h0 = hsh[0][k], h1 = hsh[1][k];
      a0 = fmaf(h0.x, w[4*k+0], a0);  a1 = fmaf(h1.x, w[4*k+0], a1);
      a0 = fmaf(h0.y, w[4*k+1], a0);  a1 = fmaf(h1.y, w[4*k+1], a1);
      a0 = fmaf(h0.z, w[4*k+2], a0);  a1 = fmaf(h1.z, w[4*k+2], a1);
      a0 = fmaf(h0.w, w[4*k+3], a0);  a1 = fmaf(h1.w, w[4*k+3], a1);
    }
    if (LAYER == 0){
      if (more){ rn0 = P0[idxn0*GG + g]; rn1 = P0[idxn1*GG + g]; }
    }
    gbuf[0][g] = a0 + pc0;
    gbuf[1][g] = a1 + pc1;
    __syncthreads();
    if (g < 128){
      int b = g>>6, j = g&63;
      float gi = gbuf[b][j], gf = gbuf[b][64+j], gc = gbuf[b][128+j], go = gbuf[b][192+j];
      float c = csh[b][j];
      float cn = sigf(gf)*c + sigf(gi)*tanhfast(gc);
      float hn = sigf(go)*tanhfast(cn);
      csh[b][j] = cn;
      ((float*)hsh)[b*64+j] = hn;
      hout[(size_t)((b0 + b)*TT + tt)*DD + dir*HH + j] = f2bf(hn);
    }
    __syncthreads();
    pc0 = rn0; pc1 = rn1;
  }
}

// ---- MFMA GEMM: C[M x N] = A[M x 128](bf16) @ B[N x 128](bf16)^T + bias ----
// Block tile 128(M) x 64(N), K=128 staged once. 4 waves, wave tile 64x32.
// LDS: As 128x136 bf16 (34 KiB) + Bs 64x136 bf16 (17 KiB) = 51 KiB.
__global__ __launch_bounds__(256, 2)
void k_gemm_mfma(const unsigned short* __restrict__ A, const unsigned short* __restrict__ Bw,
                 const float* __restrict__ bias, void* __restrict__ C,
                 const int N, const int obf16)
{
  __shared__ __align__(16) unsigned short As[128*136];
  __shared__ __align__(16) unsigned short Bs[64*136];
  const int tid = threadIdx.x;
  const size_t m0 = (size_t)blockIdx.y * 128;
  const int n0 = blockIdx.x * 64;
  #pragma unroll
  for (int i=0;i<8;i++){
    int idx = tid + i*256;           // 2048 chunks of 8 bf16 = 128x128
    int r = idx >> 4, c = idx & 15;
    *(ushort8_t*)(As + r*136 + c*8) = *(const ushort8_t*)(A + (m0+r)*128 + c*8);
  }
  #pragma unroll
  for (int i=0;i<4;i++){
    int idx = tid + i*256;           // 1024 chunks = 64x128
    int r = idx >> 4, c = idx & 15;
    *(ushort8_t*)(Bs + r*136 + c*8) = *(const ushort8_t*)(Bw + (size_t)(n0+r)*128 + c*8);
  }
  __syncthreads();
  const int lane = tid & 63, wid = tid >> 6;
  const int wm = (wid & 1) * 64, wn = (wid >> 1) * 32;
  const int l16 = lane & 15, q = lane >> 4;
  f4v acc[4][2];
  #pragma unroll
  for (int i=0;i<4;i++){
    #pragma unroll
    for (int j=0;j<2;j++){ acc[i][j][0]=0.f; acc[i][j][1]=0.f; acc[i][j][2]=0.f; acc[i][j][3]=0.f; }
  }
  #pragma unroll
  for (int ks=0; ks<4; ks++){
    const int kb = ks*32 + q*8;
    s8v a[4], b[2];
    #pragma unroll
    for (int mt=0;mt<4;mt++) a[mt] = *(const s8v*)(As + (wm + mt*16 + l16)*136 + kb);
    #pragma unroll
    for (int nt=0;nt<2;nt++) b[nt] = *(const s8v*)(Bs + (wn + nt*16 + l16)*136 + kb);
    #pragma unroll
    for (int mt=0;mt<4;mt++){
      #pragma unroll
      for (int nt=0;nt<2;nt++){
        acc[mt][nt] = __builtin_amdgcn_mfma_f32_16x16x32_bf16(a[mt], b[nt], acc[mt][nt], 0, 0, 0);
      }
    }
  }
  #pragma unroll
  for (int mt=0;mt<4;mt++){
    #pragma unroll
    for (int nt=0;nt<2;nt++){
      int col = n0 + wn + nt*16 + l16;
      float bv = bias[col];
      #pragma unroll
      for (int r=0;r<4;r++){
        size_t row = m0 + wm + mt*16 + q*4 + r;
        float v = acc[mt][nt][r] + bv;
        if (obf16) ((unsigned short*)C)[row*N + col] = f2bf(v);
        else       ((float*)C)[row*N + col] = v;
      }
    }
  }
}

// ---------------- gold-path score: 1 block (64 thr) per batch row ----------------
__global__ void k_score(const int* __restrict__ x, const int* __restrict__ tags,
                        const float* __restrict__ em, const float* __restrict__ startv,
                        const float* __restrict__ endv, const float* __restrict__ trans,
                        float* __restrict__ score)
{
  int b = blockIdx.x, lane = threadIdx.x;
  float s = 0.f; int cnt = 0;
  for (int t = lane; t < TT; t += 64){
    int xv = x[b*TT + t];
    int m = (xv != 0);
    cnt += m;
    if (t >= 1 && m){
      int tp = tags[b*TT + t - 1], tc = tags[b*TT + t];
      s += trans[tp*VV + tc] + em[(size_t)(b*TT + t)*VV + tc];
    }
  }
  #pragma unroll
  for (int o=32;o>0;o>>=1){ s += __shfl_down(s,o,64); cnt += __shfl_down(cnt,o,64); }
  if (lane==0){
    int t0 = tags[b*TT];
    s += startv[t0] + em[(size_t)(b*TT)*VV + t0];
    int lt = tags[b*TT + cnt - 1];
    s += endv[lt];
    score[b] = s;
  }
}

// ---------------- CRF partition scan in linear domain: 1 block per batch row ----------------
__global__ __launch_bounds__(256,2)
void k_crf(const int* __restrict__ x, const float* __restrict__ em,
           const float* __restrict__ etrans, const float* __restrict__ startv,
           const float* __restrict__ eend, float* __restrict__ part)
{
  const int b = blockIdx.x;
  const int j = threadIdx.x & 127;
  const int ih = threadIdx.x >> 7;     // i-range half
  const int wid = threadIdx.x >> 6;
  const int lane = threadIdx.x & 63;
  float et[64];
  #pragma unroll
  for (int u=0;u<64;u++) et[u] = etrans[(ih*64+u)*VV + j];
  __shared__ __align__(16) float abuf[128];
  __shared__ float spbuf[128];
  __shared__ float red[4];
  float L = 0.f, myA = 0.f;
  {
    float e = 0.f;
    if (ih==0){
      e = __expf(startv[j] + em[(size_t)(b*TT)*VV + j]);
      float wsum = e;
      #pragma unroll
      for (int o=32;o>0;o>>=1) wsum += __shfl_down(wsum,o,64);
      if (lane==0) red[wid] = wsum;
    }
    __syncthreads();
    float Z = red[0]+red[1];
    L = logf(Z);
    if (ih==0){ myA = e/Z; abuf[j] = myA; }
    __syncthreads();
  }
  for (int t=1;t<TT;t++){
    if (x[b*TT + t] == 0) break;       // mask is a contiguous prefix
    float emv = 0.f;
    if (ih==0) emv = em[(size_t)(b*TT + t)*VV + j];
    float s = 0.f;
    const float4* av = (const float4*)(abuf + ih*64);
    #pragma unroll
    for (int i4=0;i4<16;i4++){
      float4 a = av[i4];
      s = fmaf(a.x, et[4*i4+0], s);
      s = fmaf(a.y, et[4*i4+1], s);
      s = fmaf(a.z, et[4*i4+2], s);
      s = fmaf(a.w, et[4*i4+3], s);
    }
    if (ih==1) spbuf[j] = s;
    __syncthreads();
    float raw = 0.f;
    if (ih==0){
      raw = (s + spbuf[j]) * __expf(emv);
      float wsum = raw;
      #pragma unroll
      for (int o=32;o>0;o>>=1) wsum += __shfl_down(wsum,o,64);
      if (lane==0) red[wid] = wsum;
    }
    __syncthreads();
    float Zt = red[0]+red[1];
    L += logf(Zt);
    if (ih==0){ myA = raw/Zt; abuf[j] = myA; }
    __syncthreads();
  }
  {
    float v = 0.f;
    if (ih==0){
      v = myA * eend[j];
      #pragma unroll
      for (int o=32;o>0;o>>=1) v += __shfl_down(v,o,64);
      if (lane==0) red[wid] = v;
    }
    __syncthreads();
    if (threadIdx.x==0) part[b] = L + logf(red[0]+red[1]);
  }
}

__global__ void k_final(const float* __restrict__ part, const float* __restrict__ score,
                        float* __restrict__ out)
{
  __shared__ float red[8];
  int tid = threadIdx.x;
  float v = part[tid] - score[tid];
  #pragma unroll
  for (int o=32;o>0;o>>=1) v += __shfl_down(v,o,64);
  if ((tid&63)==0) red[tid>>6] = v;
  __syncthreads();
  if (tid==0){
    float s = 0.f;
    #pragma unroll
    for (int i=0;i<8;i++) s += red[i];
    out[0] = s / (float)BB;
  }
}

extern "C" void kernel_launch(void* const* d_in, const int* in_sizes, int n_in,
                              void* d_out, int out_size, void* d_ws, size_t ws_size,
                              hipStream_t stream)
{
  const int*   x        = (const int*)d_in[0];
  const int*   tags     = (const int*)d_in[1];
  const float* emb      = (const float*)d_in[2];
  const float* w_ih_l0  = (const float*)d_in[3];
  const float* w_hh_l0  = (const float*)d_in[4];
  const float* b_ih_l0  = (const float*)d_in[5];
  const float* b_hh_l0  = (const float*)d_in[6];
  const float* w_ih_l0r = (const float*)d_in[7];
  const float* w_hh_l0r = (const float*)d_in[8];
  const float* b_ih_l0r = (const float*)d_in[9];
  const float* b_hh_l0r = (const float*)d_in[10];
  const float* w_ih_l1  = (const float*)d_in[11];
  const float* w_hh_l1  = (const float*)d_in[12];
  const float* b_ih_l1  = (const float*)d_in[13];
  const float* b_hh_l1  = (const float*)d_in[14];
  const float* w_ih_l1r = (const float*)d_in[15];
  const float* w_hh_l1r = (const float*)d_in[16];
  const float* b_ih_l1r = (const float*)d_in[17];
  const float* b_hh_l1r = (const float*)d_in[18];
  const float* lin_w    = (const float*)d_in[19];
  const float* lin_b    = (const float*)d_in[20];
  const float* crf_start= (const float*)d_in[21];
  const float* crf_end  = (const float*)d_in[22];
  const float* crf_trans= (const float*)d_in[23];

  char* ws = (char*)d_ws;
  float*          P0f    = (float*)(ws + 0);          // 131072 B
  float*          P0b    = (float*)(ws + 131072);     // 131072 B
  unsigned short* wB1    = (unsigned short*)(ws + 262144);  // 512x128 bf16 = 131072 B
  unsigned short* linB   = (unsigned short*)(ws + 393216);  // 128x128 bf16 = 32768 B
  float*          bias1  = (float*)(ws + 425984);     // 2048 B
  float*          etrans = (float*)(ws + 428032);     // 65536 B
  float*          eend   = (float*)(ws + 493568);     // 512 B
  float*          scoreA = (float*)(ws + 494080);     // 2048 B
  float*          partA  = (float*)(ws + 496128);     // 2048 B
  const size_t MB1 = 1ull<<20;
  unsigned short* hbuf = (unsigned short*)(ws + MB1);              // 32 MiB bf16 (B*T*128)
  unsigned short* pre1 = (unsigned short*)(ws + MB1 + 33554432ull); // 128 MiB bf16 (B*T*512)
  float*          em   = (float*)(ws + MB1 + 33554432ull);          // aliases pre1 (dead by then)

  k_prep<<<dim3(401), dim3(256), 0, stream>>>(
      emb, w_ih_l0,b_ih_l0,b_hh_l0, w_ih_l0r,b_ih_l0r,b_hh_l0r,
      w_ih_l1,b_ih_l1,b_hh_l1, w_ih_l1r,b_ih_l1r,b_hh_l1r,
      lin_w, crf_trans, crf_end,
      P0f,P0b,wB1,linB,bias1,etrans,eend);

  k_lstm<0><<<dim3(512), dim3(256), 0, stream>>>(
      x, P0f, P0b, pre1, w_hh_l0, w_hh_l0r, hbuf);

  k_gemm_mfma<<<dim3(8,1024), dim3(256), 0, stream>>>(
      hbuf, wB1, bias1, (void*)pre1, 512, 1);

  k_lstm<1><<<dim3(512), dim3(256), 0, stream>>>(
      x, P0f, P0b, pre1, w_hh_l1, w_hh_l1r, hbuf);

  k_gemm_mfma<<<dim3(2,1024), dim3(256), 0, stream>>>(
      hbuf, linB, lin_b, (void*)em, 128, 0);

  k_score<<<dim3(512), dim3(64), 0, stream>>>(
      x, tags, em, crf_start, crf_end, crf_trans, scoreA);

  k_crf<<<dim3(512), dim3(256), 0, stream>>>(
      x, em, etrans, crf_start, eend, partA);

  k_final<<<dim3(1), dim3(512), 0, stream>>>(partA, scoreA, (float*)d_out);
}